// Round 7
// baseline (232.967 us; speedup 1.0000x reference)
//
#include <hip/hip_runtime.h>

// VQ-VAE VectorQuantizer forward, MI355X (gfx950)
// inputs:  d_in[0] = inputs  [64,32,32,64] f32  (N=65536 rows, D=64)
//          d_in[1] = context [1] (unused)
//          d_in[2] = embeddings [64,512] f32    (D=64, K=512)
// out (flat f32): quantized[4194304] | loss[1] | perplexity[1] |
//   encodings[33554432] | encoding_indices[65536] | distances[33554432]

#define NROWS 65536
#define DIM 64
#define KCODES 512
#define ROWS_PER_BLOCK 64
#define RPT 8      // rows per wave per group
#define NGROUP 2   // groups per wave (16 rows/wave, 4 waves)

#define QUANT_OFF 0ull
#define LOSS_OFF  4194304ull
#define PERP_OFF  4194305ull
#define ENC_OFF   4194306ull
#define IDX_OFF   37748738ull
#define DIST_OFF  37814274ull

typedef float f32x4 __attribute__((ext_vector_type(4)));

__global__ __launch_bounds__(256, 4) void vq_main(
    const float* __restrict__ inp, const float* __restrict__ emb,
    float* __restrict__ out, int* __restrict__ hist,
    float* __restrict__ loss_ws)
{
    __shared__ float s_sumx2[ROWS_PER_BLOCK];     // 256 B

    const int tid  = threadIdx.x;
    const int w    = tid >> 6;                    // wave 0..3
    const int lane = tid & 63;
    const int rbase = blockIdx.x * ROWS_PER_BLOCK;
    // lane owns k = h*256 + lane*4 + j (h=0,1; j=0..3)

    // ---- per-row ||x||^2 (one barrier, then waves free-run) ----
    if (tid < ROWS_PER_BLOCK) {
        const f32x4* xr = (const f32x4*)(inp + (size_t)(rbase + tid) * DIM);
        float s0 = 0.f, s1 = 0.f, s2 = 0.f, s3 = 0.f;
#pragma unroll
        for (int j = 0; j < 16; ++j) {
            const f32x4 v = xr[j];
            s0 = fmaf(v.x, v.x, s0); s1 = fmaf(v.y, v.y, s1);
            s2 = fmaf(v.z, v.z, s2); s3 = fmaf(v.w, v.w, s3);
        }
        s_sumx2[tid] = (s0 + s1) + (s2 + s3);
    }
    __syncthreads();

    f32x4 sume2[2];
    sume2[0] = (f32x4){0.f, 0.f, 0.f, 0.f};
    sume2[1] = (f32x4){0.f, 0.f, 0.f, 0.f};
    float loss_acc = 0.f;

    const float* ebase = emb + lane * 4;

#pragma unroll 1
    for (int g = 0; g < NGROUP; ++g) {
        const int rl0 = w * (RPT * NGROUP) + g * RPT;   // wave-local row base

        float bd[RPT];
        int   ck[RPT];
#pragma unroll
        for (int r = 0; r < RPT; ++r) { bd[r] = 3.4e38f; ck[r] = 0x7fffffff; }

#pragma unroll 1
        for (int h = 0; h < 2; ++h) {
            f32x4 acc[RPT];
#pragma unroll
            for (int r = 0; r < RPT; ++r) acc[r] = (f32x4){0.f, 0.f, 0.f, 0.f};

#pragma unroll 1
            for (int dq = 0; dq < 16; ++dq) {
                f32x4 e4[4];
#pragma unroll
                for (int sub = 0; sub < 4; ++sub)
                    e4[sub] = *(const f32x4*)(ebase + (dq * 4 + sub) * KCODES
                                              + h * 256);
                if (g == 0) {                     // fold ||e||^2 into group 0
#pragma unroll
                    for (int sub = 0; sub < 4; ++sub)
                        sume2[h] = sume2[h] + e4[sub] * e4[sub];
                }
#pragma unroll
                for (int r = 0; r < RPT; ++r) {
                    // wave-uniform VMEM broadcast (addr depends on tid>>6 ->
                    // not block-uniform -> stays on the vector path, L1-hit)
                    const f32x4 xv = *(const f32x4*)(
                        inp + (size_t)(rbase + rl0 + r) * DIM + dq * 4);
                    acc[r] = acc[r] + xv.x * e4[0];
                    acc[r] = acc[r] + xv.y * e4[1];
                    acc[r] = acc[r] + xv.z * e4[2];
                    acc[r] = acc[r] + xv.w * e4[3];
                }
            }

            // distances for this half: NT store now (overlaps later compute),
            // track per-lane best
#pragma unroll
            for (int r = 0; r < RPT; ++r) {
                const float sx2 = s_sumx2[rl0 + r];
                const f32x4 dd = (sume2[h] + sx2) + (-2.f) * acc[r];

                f32x4* dp = (f32x4*)(out + DIST_OFF
                                     + (size_t)(rbase + rl0 + r) * KCODES);
                __builtin_nontemporal_store(dd, dp + h * 64 + lane);

                const float m = fminf(fminf(dd.x, dd.y), fminf(dd.z, dd.w));
                int j = 3;                         // descending -> smallest j
                if (dd.z == m) j = 2;
                if (dd.y == m) j = 1;
                if (dd.x == m) j = 0;
                if (m < bd[r]) {                   // strict: h=0 wins ties
                    bd[r] = m;
                    ck[r] = h * 256 + lane * 4 + j;
                }
            }
        }

        // ---- epilogue: cross-lane argmin, enc/quant/idx/hist/loss ----
#pragma unroll
        for (int r = 0; r < RPT; ++r) {
            const int row = rbase + rl0 + r;

            float fd = bd[r];
#pragma unroll
            for (int off = 32; off; off >>= 1)
                fd = fminf(fd, __shfl_xor(fd, off));
            int c2 = (bd[r] == fd) ? ck[r] : 0x7fffffff;
#pragma unroll
            for (int off = 32; off; off >>= 1) {
                const int ok = __shfl_xor(c2, off);
                c2 = ok < c2 ? ok : c2;
            }

            // encodings one-hot: 2 contiguous f32x4 NT stores
            f32x4* ep = (f32x4*)(out + ENC_OFF) + (size_t)row * 128;
            const int cq = c2 >> 2;
            f32x4 v0 = {0.f, 0.f, 0.f, 0.f};
            f32x4 v1 = {0.f, 0.f, 0.f, 0.f};
            if (cq == lane) {
                v0.x = (c2 & 3) == 0 ? 1.f : 0.f;
                v0.y = (c2 & 3) == 1 ? 1.f : 0.f;
                v0.z = (c2 & 3) == 2 ? 1.f : 0.f;
                v0.w = (c2 & 3) == 3 ? 1.f : 0.f;
            }
            if (cq == 64 + lane) {
                v1.x = (c2 & 3) == 0 ? 1.f : 0.f;
                v1.y = (c2 & 3) == 1 ? 1.f : 0.f;
                v1.z = (c2 & 3) == 2 ? 1.f : 0.f;
                v1.w = (c2 & 3) == 3 ? 1.f : 0.f;
            }
            __builtin_nontemporal_store(v0, ep + lane);
            __builtin_nontemporal_store(v1, ep + 64 + lane);

            // quantized row: gather E[lane][c2] (L2-hot), coalesced store
            const float q = emb[lane * KCODES + c2];
            out[QUANT_OFF + (size_t)row * DIM + lane] = q;

            if (lane == 0) {
                out[IDX_OFF + row] = (float)c2;
                atomicAdd(&hist[c2], 1);
                loss_acc += fd;                   // sum_d(q-x)^2 == min dist
            }
        }
    }

    if (lane == 0) atomicAdd(loss_ws, loss_acc);
}

__global__ __launch_bounds__(512) void vq_final(
    const int* __restrict__ hist, const float* __restrict__ loss_ws,
    float* __restrict__ out)
{
    __shared__ float s_red[8];
    const int tid = threadIdx.x;
    const int w = tid >> 6, lane = tid & 63;

    float p = (float)hist[tid] * (1.f / 65536.f);
    float t = p * logf(p + 1e-10f);   // p==0 -> 0
#pragma unroll
    for (int off = 32; off; off >>= 1) t += __shfl_xor(t, off);
    if (lane == 0) s_red[w] = t;
    __syncthreads();
    if (tid == 0) {
        float s = 0.f;
#pragma unroll
        for (int i = 0; i < 8; ++i) s += s_red[i];
        out[PERP_OFF] = expf(-s);
        // loss = (1 + 0.25) * mean((q - x)^2) over 4194304 elements
        out[LOSS_OFF] = loss_ws[0] * (1.25f / 4194304.f);
    }
}

extern "C" void kernel_launch(void* const* d_in, const int* in_sizes, int n_in,
                              void* d_out, int out_size, void* d_ws, size_t ws_size,
                              hipStream_t stream) {
    const float* inp = (const float*)d_in[0];
    const float* emb = (const float*)d_in[2];
    float* out = (float*)d_out;
    int*   hist    = (int*)d_ws;                       // 512 ints
    float* loss_ws = (float*)((char*)d_ws + 2048);     // 1 float

    (void)hipMemsetAsync(d_ws, 0, 2052, stream);
    vq_main<<<dim3(NROWS / ROWS_PER_BLOCK), dim3(256), 0, stream>>>(
        inp, emb, out, hist, loss_ws);
    vq_final<<<dim3(1), dim3(512), 0, stream>>>(hist, loss_ws, out);
}